// Round 7
// baseline (144.790 us; speedup 1.0000x reference)
//
#include <hip/hip_runtime.h>
#include <math.h>

// Problem constants (GroupedKANLayer): B=2, C=31, D=7, H=W=192
#define NBATCH 2
#define NC 31
#define ND 7
#define NH 192
#define NW 192
#define HW (NH * NW)            // 36864
#define NP (NBATCH * HW)        // 73728 pixels
#define NBASIS 8
#define CLEN 56                 // ND * NBASIS
#define KP 70                   // CLEN + ND + ND

// ctx_mean grid split: first N4/256 blocks do the mean, next 90 do bf16
// weight transform.
#define N4 (NBATCH * NC * (HW / 4))     // 571392 = 2232 * 256 exactly
#define GWB_N (9 * 80 * 32)             // 23040 bf16 weights, padded

// fused-kernel LDS: zero-padded spline table, 126 rows x 64 px f32:
//   row = d*16 + s, s = j+4, j = -4..11 (valid j 0..7 -> s 4..11, zeros
//   elsewhere); rows 112..118 = uw[d], 119..125 = rw[d].
// 126*64*4 = 32256 B -> 5 blocks/CU LDS cap (20 waves/CU). The phase-1
// ctx halo B-tile (12672 B) overlays the same memory (disjoint lifetime).
#define SROWS 126
#define SMEM_BYTES (SROWS * 64 * 4)     // 32256 B
#define B_WORDS (3 * 66 * 32)           // 6336 ushorts (12672 B)

typedef __attribute__((ext_vector_type(8))) short s16x8;
typedef __attribute__((ext_vector_type(4))) float f32x4;

__device__ __forceinline__ unsigned short f2bf(float f)
{
    unsigned u = __float_as_uint(f);
    u += 0x7FFFu + ((u >> 16) & 1u);     // round-to-nearest-even
    return (unsigned short)(u >> 16);
}

// ---------------------------------------------------------------------------
// Kernel 1: ctx = mean_d x (float4, 16 B/lane) + folded weight transform:
// gwb[s][m(80)][ic(32)] = bf16(gw[m][ic][dy][dx]), zero-padded.
// ---------------------------------------------------------------------------
__global__ __launch_bounds__(256) void ctx_mean_kernel(
    const float4* __restrict__ x4, float4* __restrict__ ctx4,
    const float* __restrict__ gw, unsigned short* __restrict__ gwb)
{
    const int HW4 = HW / 4;
    int idx = blockIdx.x * 256 + threadIdx.x;
    if (idx < N4) {
        int hw4 = idx % HW4;
        int bc  = idx / HW4;
        const float4* src = x4 + (size_t)bc * (ND * HW4) + hw4;
        float4 a = src[0];
#pragma unroll
        for (int d = 1; d < ND; ++d) {
            float4 v = src[d * HW4];
            a.x += v.x; a.y += v.y; a.z += v.z; a.w += v.w;
        }
        const float inv = 1.0f / 7.0f;
        a.x *= inv; a.y *= inv; a.z *= inv; a.w *= inv;
        ctx4[idx] = a;
        return;
    }
    int e = idx - N4;
    if (e < GWB_N) {
        int s  = e / 2560;          // 80*32
        int r  = e - s * 2560;
        int m  = r >> 5;
        int ic = r & 31;
        float v = (m < KP && ic < NC) ? gw[m * (NC * 9) + ic * 9 + s] : 0.f;
        gwb[e] = f2bf(v);
    }
}

// ---------------------------------------------------------------------------
// kan helpers
// ---------------------------------------------------------------------------
// Zero-padded-table spline: one addr + 4 ds_read_b32 (offset imm) + 4 FMA.
// i clamped to [-1,11]: out-of-range taps read stored zeros (matches the
// reference, whose basis list simply has no j<0 / j>7 entries).
__device__ __forceinline__ float spline2(float xv, const float* cbl, int d)
{
    float t = __builtin_fmaf(xv, 2.5f, 5.5f);   // (xv + 2.2) * 2.5
    float fi = floorf(t);
    float u = t - fi;                            // in [0,1) always
    int i = (int)fi;
    i = min(max(i, -1), 11);
    float u2 = u * u, u3 = u2 * u;
    float um = 1.f - u;
    float w0 = um * um * um * (1.f / 6.f);
    float w3 = u3 * (1.f / 6.f);
    float w1 = (3.f * u3 - 6.f * u2 + 4.f) * (1.f / 6.f);
    float w2 = 1.f - w0 - w1 - w3;              // partition of unity
    const float* p = cbl + (d * 16 + 1 + i) * 64;   // slot s=i+1 .. i+4
    return w0 * p[0] + w1 * p[64] + w2 * p[128] + w3 * p[192];
}

__device__ __forceinline__ float silu(float xv)
{
    return xv / (1.f + __expf(-xv));
}

// ---------------------------------------------------------------------------
// Kernel 2 (R11, FUSED conv+kan, channel-split): grid (1152, 2).
// Phase 1 (conv): 9 accumulated GEMMs M=80,K=32, bf16 MFMA; A-fragments
//   straight from global gwb (L2-resident); ctx halo B-tile in LDS.
//   Duplicated across blockIdx.y (cheap: MfmaUtil ~3%).
// Phase 2: zero the pad rows + scatter D-fragments into the padded spline
//   table (32.3 KB, overlays dead B region).
// Phase 3 (kan): blockIdx.y picks channel half (y=0: c0-15, y=1: c16-30,
//   kan-v10 mapping, c27 dup benign). 4 channels/wave = 2 pairs/thread,
//   x loads for pair 0 hoisted above the phase-1 barrier.
// 2304 blocks x 4 waves = 9216 waves -> machine fully subscribed;
// LDS 32.3 KB -> 5 blocks/CU cap.
// ---------------------------------------------------------------------------
__global__ __launch_bounds__(256, 4) void fused_kernel(
    const float* __restrict__ ctx, const unsigned short* __restrict__ gwb,
    const float* __restrict__ gb, const float* __restrict__ x,
    float* __restrict__ out)
{
    __shared__ __align__(16) unsigned char smem[SMEM_BYTES];
    unsigned short* Bt = (unsigned short*)smem;    // phase 1
    float* scoef = (float*)smem;                   // phases 2-3 (overlay)

    const int tid  = threadIdx.x;
    const int lane = tid & 63;
    const int wv   = tid >> 6;
    const int gr   = blockIdx.x / 3;          // global row 0..383
    const int x0   = (blockIdx.x % 3) * 64;
    const int b    = gr / NH;
    const int y    = gr - b * NH;

    // stage B: thread = halo cell (row 0..2, col 0..65); 31 strided ctx
    // reads -> bf16 pack (ic-contiguous, ic=31 padded 0) -> 4 b128 writes.
    if (tid < 3 * 66) {
        int row = tid / 66;
        int col = tid - row * 66;
        int gy = y + row - 1, gx = x0 + col - 1;
        bool ok = (gy >= 0) && (gy < NH) && (gx >= 0) && (gx < NW);
        int cgy = ok ? gy : 0, cgx = ok ? gx : 0;
        const float* src = ctx + (size_t)(b * NC) * HW + cgy * NW + cgx;
        unsigned dw[16];
        if (ok) {
            float v[NC];
#pragma unroll
            for (int ic = 0; ic < NC; ++ic) v[ic] = src[(size_t)ic * HW];
#pragma unroll
            for (int j = 0; j < 16; ++j) {
                unsigned lo = f2bf(v[2 * j]);
                unsigned hi = (2 * j + 1 < NC) ? (unsigned)f2bf(v[2 * j + 1]) : 0u;
                dw[j] = lo | (hi << 16);
            }
        } else {
#pragma unroll
            for (int j = 0; j < 16; ++j) dw[j] = 0u;
        }
        uint4* dst = (uint4*)(Bt + tid * 32);
#pragma unroll
        for (int q = 0; q < 4; ++q)
            dst[q] = make_uint4(dw[4 * q], dw[4 * q + 1], dw[4 * q + 2], dw[4 * q + 3]);
    }

    // hoist phase-3 pair-0 x loads: HBM latency hides under conv MFMAs.
    // channel mapping (kan-v10): y=0 -> wv*4, y=1 -> wv==3 ? 27 : 16+wv*4
    const int c0 = (blockIdx.y == 0) ? wv * 4
                                     : ((wv == 3) ? 27 : 16 + wv * 4);
    const int hw = y * NW + x0 + lane;
    const float* xb = x + (size_t)(b * NC) * (ND * HW) + hw;
    float cur[2][ND];
#pragma unroll
    for (int d = 0; d < ND; ++d) {
        cur[0][d] = xb[((size_t)c0 * ND + d) * HW];
        cur[1][d] = xb[((size_t)(c0 + 1) * ND + d) * HW];
    }
    __syncthreads();

    // phase 1: MFMA. A row=lane&15, k=(lane>>4)*8+j; B col=lane&15, same k;
    // D col=lane&15, row=(lane>>4)*4+j  (m89-verified layouts).
    const int lm = lane & 15;
    const int kb = lane >> 4;

    f32x4 acc[5];
#pragma unroll
    for (int mt = 0; mt < 5; ++mt)
#pragma unroll
        for (int j = 0; j < 4; ++j) {
            int m = mt * 16 + kb * 4 + j;
            acc[mt][j] = (m < KP) ? gb[m] : 0.f;
        }

    const unsigned short* ap = gwb + lm * 32 + kb * 8;      // GLOBAL (L2)
    const unsigned short* bp = Bt + (wv * 16 + lm) * 32 + kb * 8;

#pragma unroll
    for (int s = 0; s < 9; ++s) {
        const int dy = s / 3, dx = s % 3;
        s16x8 bf = *(const s16x8*)(bp + (dy * 66 + dx) * 32);
#pragma unroll
        for (int mt = 0; mt < 5; ++mt) {
            s16x8 af = *(const s16x8*)(ap + (s * 80 + mt * 16) * 32);
            acc[mt] = __builtin_amdgcn_mfma_f32_16x16x32_bf16(af, bf, acc[mt], 0, 0, 0);
        }
    }
    __syncthreads();            // B dead

    // phase 2a: zero the 56 pad rows (8 per d: slots 0-3 and 12-15)
    for (int f = tid; f < 56 * 64; f += 256) {
        int r  = f >> 6, px = f & 63;
        int d  = r >> 3, o = r & 7;
        int row = d * 16 + (o < 4 ? o : o + 8);
        scoef[row * 64 + px] = 0.f;
    }
    // phase 2b: scatter D-fragments. m -> row: coef m<56: (m/8)*16+4+(m%8);
    // uw/rw m=56..69: row = 56+m (uw 112..118, rw 119..125, contiguous).
    {
        const int px = wv * 16 + lm;
#pragma unroll
        for (int mt = 0; mt < 5; ++mt)
#pragma unroll
            for (int j = 0; j < 4; ++j) {
                int m = mt * 16 + kb * 4 + j;
                if (m < KP) {
                    int row = (m < CLEN) ? ((m >> 3) << 4) + 4 + (m & 7)
                                         : 56 + m;
                    scoef[row * 64 + px] = acc[mt][j];
                }
            }
    }
    __syncthreads();

    // phase 3: kan. lane = px; wave covers 4 channels (2 pairs).
    const float* cbl = scoef + lane;

    float uw[ND], rw[ND];
#pragma unroll
    for (int d = 0; d < ND; ++d) {
        uw[d] = cbl[(112 + d) * 64];
        rw[d] = cbl[(119 + d) * 64];
    }

    float* ob = out + (b * NC) * HW + hw;

    float nxt[2][ND];
#pragma unroll
    for (int pr = 0; pr < 2; ++pr) {
        int ca = c0 + 2 * pr, cb2 = ca + 1;
        if (pr == 0) {
#pragma unroll
            for (int d = 0; d < ND; ++d) {
                nxt[0][d] = xb[((size_t)(c0 + 2) * ND + d) * HW];
                nxt[1][d] = xb[((size_t)(c0 + 3) * ND + d) * HW];
            }
        }
        float sa = 0.f, sb = 0.f;
#pragma unroll
        for (int d = 0; d < ND; ++d) {
            sa += uw[d] * spline2(cur[0][d], cbl, d) + rw[d] * silu(cur[0][d]);
            sb += uw[d] * spline2(cur[1][d], cbl, d) + rw[d] * silu(cur[1][d]);
        }
        ob[(size_t)ca * HW] = sa;
        ob[(size_t)cb2 * HW] = sb;
        if (pr == 0) {
#pragma unroll
            for (int d = 0; d < ND; ++d) {
                cur[0][d] = nxt[0][d];
                cur[1][d] = nxt[1][d];
            }
        }
    }
}

// ---------------------------------------------------------------------------
extern "C" void kernel_launch(void* const* d_in, const int* in_sizes, int n_in,
                              void* d_out, int out_size, void* d_ws, size_t ws_size,
                              hipStream_t stream)
{
    const float* x  = (const float*)d_in[0];   // (2,31,7,192,192)
    const float* gw = (const float*)d_in[1];   // (70,31,3,3)
    const float* gb = (const float*)d_in[2];   // (70,)
    float* out = (float*)d_out;                // (2,31,192,192)

    float* ctx = (float*)d_ws;                             // 9.1 MB
    unsigned short* gwb = (unsigned short*)(ctx + (size_t)NBATCH * NC * HW);

    ctx_mean_kernel<<<dim3(N4 / 256 + (GWB_N + 255) / 256), 256, 0, stream>>>(
        (const float4*)x, (float4*)ctx, gw, gwb);
    fused_kernel<<<dim3(NP / 64, 2), 256, 0, stream>>>(ctx, gwb, gb, x, out);
}

// Round 8
// 134.997 us; speedup vs baseline: 1.0725x; 1.0725x over previous
//
#include <hip/hip_runtime.h>
#include <math.h>

// Problem constants (GroupedKANLayer): B=2, C=31, D=7, H=W=192
#define NBATCH 2
#define NC 31
#define ND 7
#define NH 192
#define NW 192
#define HW (NH * NW)            // 36864
#define NP (NBATCH * HW)        // 73728 pixels
#define NBASIS 8
#define CLEN 56                 // ND * NBASIS
#define KP 70                   // CLEN + ND + ND

// ctx_mean grid split: first N4/256 blocks do the mean, next 90 do bf16
// weight transform.
#define N4 (NBATCH * NC * (HW / 4))     // 571392 = 2232 * 256 exactly
#define GWB_N (9 * 80 * 32)             // 23040 bf16 weights, padded

// fused-kernel LDS: zero-padded spline table, 126 rows x 64 px f32:
//   row = d*16 + s, s = j+4, j = -4..11 (valid j 0..7 -> s 4..11, zeros
//   elsewhere); rows 112..118 = uw[d], 119..125 = rw[d].
// 126*64*4 = 32256 B. Phase-1 ctx halo B-tile (12672 B) overlays it.
#define SROWS 126
#define SMEM_BYTES (SROWS * 64 * 4)     // 32256 B
#define B_WORDS (3 * 66 * 32)           // 6336 ushorts (12672 B)

typedef __attribute__((ext_vector_type(8))) short s16x8;
typedef __attribute__((ext_vector_type(4))) float f32x4;

__device__ __forceinline__ unsigned short f2bf(float f)
{
    unsigned u = __float_as_uint(f);
    u += 0x7FFFu + ((u >> 16) & 1u);     // round-to-nearest-even
    return (unsigned short)(u >> 16);
}

// ---------------------------------------------------------------------------
// Kernel 1: ctx = mean_d x (float4, 16 B/lane) + folded weight transform:
// gwb[s][m(80)][ic(32)] = bf16(gw[m][ic][dy][dx]), zero-padded.
// ---------------------------------------------------------------------------
__global__ __launch_bounds__(256) void ctx_mean_kernel(
    const float4* __restrict__ x4, float4* __restrict__ ctx4,
    const float* __restrict__ gw, unsigned short* __restrict__ gwb)
{
    const int HW4 = HW / 4;
    int idx = blockIdx.x * 256 + threadIdx.x;
    if (idx < N4) {
        int hw4 = idx % HW4;
        int bc  = idx / HW4;
        const float4* src = x4 + (size_t)bc * (ND * HW4) + hw4;
        float4 a = src[0];
#pragma unroll
        for (int d = 1; d < ND; ++d) {
            float4 v = src[d * HW4];
            a.x += v.x; a.y += v.y; a.z += v.z; a.w += v.w;
        }
        const float inv = 1.0f / 7.0f;
        a.x *= inv; a.y *= inv; a.z *= inv; a.w *= inv;
        ctx4[idx] = a;
        return;
    }
    int e = idx - N4;
    if (e < GWB_N) {
        int s  = e / 2560;          // 80*32
        int r  = e - s * 2560;
        int m  = r >> 5;
        int ic = r & 31;
        float v = (m < KP && ic < NC) ? gw[m * (NC * 9) + ic * 9 + s] : 0.f;
        gwb[e] = f2bf(v);
    }
}

// ---------------------------------------------------------------------------
// kan helpers
// ---------------------------------------------------------------------------
// Zero-padded-table spline (HW-verified R11): one addr + 4 ds_read_b32
// (offset imm) + 4 FMA. i clamped to [-1,11]: out-of-range taps read stored
// zeros (matches reference, whose basis has no j<0 / j>7 entries).
__device__ __forceinline__ float spline2(float xv, const float* cbl, int d)
{
    float t = __builtin_fmaf(xv, 2.5f, 5.5f);   // (xv + 2.2) * 2.5
    float fi = floorf(t);
    float u = t - fi;                            // in [0,1) always
    int i = (int)fi;
    i = min(max(i, -1), 11);
    float u2 = u * u, u3 = u2 * u;
    float um = 1.f - u;
    float w0 = um * um * um * (1.f / 6.f);
    float w3 = u3 * (1.f / 6.f);
    float w1 = (3.f * u3 - 6.f * u2 + 4.f) * (1.f / 6.f);
    float w2 = 1.f - w0 - w1 - w3;              // partition of unity
    const float* p = cbl + (d * 16 + 1 + i) * 64;   // slot s=i+1 .. i+4
    return w0 * p[0] + w1 * p[64] + w2 * p[128] + w3 * p[192];
}

__device__ __forceinline__ float silu(float xv)
{
    return xv / (1.f + __expf(-xv));
}

// ---------------------------------------------------------------------------
// Kernel 2 (R12 = R10 single-pass structure + R11 padded spline table):
// grid = 1152 blocks, block = 64-px row strip, NO channel split (R11's
// 2-way split duplicated ctx staging + conv: FETCH +22 MB, regression).
// Phase 1 (conv): 9 accumulated GEMMs M=80,K=32, bf16 MFMA; A-fragments
//   straight from global gwb (L2-resident); ctx halo B-tile in LDS.
// Phase 2: zero pad rows + scatter D-fragments into padded spline table.
// Phase 3 (kan): 4 waves x 8 channels (c30 dup on wave 3, benign);
//   4 channel-pairs/thread, 2-deep cur/nxt prefetch; pair-0 x loads
//   hoisted above the phase-1 barrier.
// ---------------------------------------------------------------------------
__global__ __launch_bounds__(256, 4) void fused_kernel(
    const float* __restrict__ ctx, const unsigned short* __restrict__ gwb,
    const float* __restrict__ gb, const float* __restrict__ x,
    float* __restrict__ out)
{
    __shared__ __align__(16) unsigned char smem[SMEM_BYTES];
    unsigned short* Bt = (unsigned short*)smem;    // phase 1
    float* scoef = (float*)smem;                   // phases 2-3 (overlay)

    const int tid  = threadIdx.x;
    const int lane = tid & 63;
    const int wv   = tid >> 6;
    const int gr   = blockIdx.x / 3;          // global row 0..383
    const int x0   = (blockIdx.x % 3) * 64;
    const int b    = gr / NH;
    const int y    = gr - b * NH;

    // stage B: thread = halo cell (row 0..2, col 0..65); 31 strided ctx
    // reads -> bf16 pack (ic-contiguous, ic=31 padded 0) -> 4 b128 writes.
    if (tid < 3 * 66) {
        int row = tid / 66;
        int col = tid - row * 66;
        int gy = y + row - 1, gx = x0 + col - 1;
        bool ok = (gy >= 0) && (gy < NH) && (gx >= 0) && (gx < NW);
        int cgy = ok ? gy : 0, cgx = ok ? gx : 0;
        const float* src = ctx + (size_t)(b * NC) * HW + cgy * NW + cgx;
        unsigned dw[16];
        if (ok) {
            float v[NC];
#pragma unroll
            for (int ic = 0; ic < NC; ++ic) v[ic] = src[(size_t)ic * HW];
#pragma unroll
            for (int j = 0; j < 16; ++j) {
                unsigned lo = f2bf(v[2 * j]);
                unsigned hi = (2 * j + 1 < NC) ? (unsigned)f2bf(v[2 * j + 1]) : 0u;
                dw[j] = lo | (hi << 16);
            }
        } else {
#pragma unroll
            for (int j = 0; j < 16; ++j) dw[j] = 0u;
        }
        uint4* dst = (uint4*)(Bt + tid * 32);
#pragma unroll
        for (int q = 0; q < 4; ++q)
            dst[q] = make_uint4(dw[4 * q], dw[4 * q + 1], dw[4 * q + 2], dw[4 * q + 3]);
    }

    // hoist phase-3 pair-0 x loads: HBM latency hides under conv MFMAs
    const int hw = y * NW + x0 + lane;
    const float* xb = x + (size_t)(b * NC) * (ND * HW) + hw;
    const int c0 = wv * 8;
    float cur[2][ND];
    {
        int ca = min(c0, 30), cb2 = min(c0 + 1, 30);
#pragma unroll
        for (int d = 0; d < ND; ++d) {
            cur[0][d] = xb[((size_t)ca * ND + d) * HW];
            cur[1][d] = xb[((size_t)cb2 * ND + d) * HW];
        }
    }
    __syncthreads();

    // phase 1: MFMA. A row=lane&15, k=(lane>>4)*8+j; B col=lane&15, same k;
    // D col=lane&15, row=(lane>>4)*4+j  (m89-verified layouts).
    const int lm = lane & 15;
    const int kb = lane >> 4;

    f32x4 acc[5];
#pragma unroll
    for (int mt = 0; mt < 5; ++mt)
#pragma unroll
        for (int j = 0; j < 4; ++j) {
            int m = mt * 16 + kb * 4 + j;
            acc[mt][j] = (m < KP) ? gb[m] : 0.f;
        }

    const unsigned short* ap = gwb + lm * 32 + kb * 8;      // GLOBAL (L2)
    const unsigned short* bp = Bt + (wv * 16 + lm) * 32 + kb * 8;

#pragma unroll
    for (int s = 0; s < 9; ++s) {
        const int dy = s / 3, dx = s % 3;
        s16x8 bf = *(const s16x8*)(bp + (dy * 66 + dx) * 32);
#pragma unroll
        for (int mt = 0; mt < 5; ++mt) {
            s16x8 af = *(const s16x8*)(ap + (s * 80 + mt * 16) * 32);
            acc[mt] = __builtin_amdgcn_mfma_f32_16x16x32_bf16(af, bf, acc[mt], 0, 0, 0);
        }
    }
    __syncthreads();            // B dead

    // phase 2a: zero the 56 pad rows (8 per d: slots 0-3 and 12-15)
    for (int f = tid; f < 56 * 64; f += 256) {
        int r  = f >> 6, px = f & 63;
        int d  = r >> 3, o = r & 7;
        int row = d * 16 + (o < 4 ? o : o + 8);
        scoef[row * 64 + px] = 0.f;
    }
    // phase 2b: scatter D-fragments. m -> row: coef m<56: (m/8)*16+4+(m%8);
    // uw/rw m=56..69: row = 56+m (uw 112..118, rw 119..125).
    {
        const int px = wv * 16 + lm;
#pragma unroll
        for (int mt = 0; mt < 5; ++mt)
#pragma unroll
            for (int j = 0; j < 4; ++j) {
                int m = mt * 16 + kb * 4 + j;
                if (m < KP) {
                    int row = (m < CLEN) ? ((m >> 3) << 4) + 4 + (m & 7)
                                         : 56 + m;
                    scoef[row * 64 + px] = acc[mt][j];
                }
            }
    }
    __syncthreads();

    // phase 3: kan. lane = px; wave wv covers channels wv*8 .. wv*8+7
    // (clamped to 30; wave 3 computes c30 twice -> same value, benign).
    const float* cbl = scoef + lane;

    float uw[ND], rw[ND];
#pragma unroll
    for (int d = 0; d < ND; ++d) {
        uw[d] = cbl[(112 + d) * 64];
        rw[d] = cbl[(119 + d) * 64];
    }

    float* ob = out + (b * NC) * HW + hw;

    float nxt[2][ND];
#pragma unroll
    for (int pr = 0; pr < 4; ++pr) {
        int ca = min(c0 + 2 * pr, 30), cb2 = min(c0 + 2 * pr + 1, 30);
        if (pr < 3) {
            int na = min(c0 + 2 * pr + 2, 30), nb = min(c0 + 2 * pr + 3, 30);
#pragma unroll
            for (int d = 0; d < ND; ++d) {
                nxt[0][d] = xb[((size_t)na * ND + d) * HW];
                nxt[1][d] = xb[((size_t)nb * ND + d) * HW];
            }
        }
        float sa = 0.f, sb = 0.f;
#pragma unroll
        for (int d = 0; d < ND; ++d) {
            sa += uw[d] * spline2(cur[0][d], cbl, d) + rw[d] * silu(cur[0][d]);
            sb += uw[d] * spline2(cur[1][d], cbl, d) + rw[d] * silu(cur[1][d]);
        }
        ob[(size_t)ca * HW] = sa;
        ob[(size_t)cb2 * HW] = sb;
        if (pr < 3) {
#pragma unroll
            for (int d = 0; d < ND; ++d) {
                cur[0][d] = nxt[0][d];
                cur[1][d] = nxt[1][d];
            }
        }
    }
}

// ---------------------------------------------------------------------------
extern "C" void kernel_launch(void* const* d_in, const int* in_sizes, int n_in,
                              void* d_out, int out_size, void* d_ws, size_t ws_size,
                              hipStream_t stream)
{
    const float* x  = (const float*)d_in[0];   // (2,31,7,192,192)
    const float* gw = (const float*)d_in[1];   // (70,31,3,3)
    const float* gb = (const float*)d_in[2];   // (70,)
    float* out = (float*)d_out;                // (2,31,192,192)

    float* ctx = (float*)d_ws;                             // 9.1 MB
    unsigned short* gwb = (unsigned short*)(ctx + (size_t)NBATCH * NC * HW);

    ctx_mean_kernel<<<dim3(N4 / 256 + (GWB_N + 255) / 256), 256, 0, stream>>>(
        (const float4*)x, (float4*)ctx, gw, gwb);
    fused_kernel<<<dim3(NP / 64), 256, 0, stream>>>(ctx, gwb, gb, x, out);
}